// Round 1
// baseline (176.227 us; speedup 1.0000x reference)
//
#include <hip/hip_runtime.h>
#include <stdint.h>
#include <stddef.h>

typedef __attribute__((ext_vector_type(8))) short bf16x8;
typedef __attribute__((ext_vector_type(4))) float f32x4;

#define NROWS 400000
#define KC 128
#define DIMS 64
#define NTILES (NROWS / 16)

__device__ __forceinline__ short f2bf(float f) {
    union { float f; uint32_t u; } v; v.f = f;
    uint32_t u = v.u;
    // round-to-nearest-even bf16 (inputs are finite normals)
    uint32_t r = (u + 0x7FFFu + ((u >> 16) & 1u)) >> 16;
    return (short)r;
}

// K1: per wave, one 16-row x 128-col tile. MFMA 16x16x32 bf16.
// A layout: lane holds A[lane&15][8*(lane>>4)+i], i=0..7 (per k-half of 32)
// B layout: lane holds B[8*(lane>>4)+i][lane&15]
// D layout (m89-verified): D[4*(lane>>4)+r][lane&15], r = reg 0..3
__global__ __launch_bounds__(256) void k1_qcolsum(
        const float* __restrict__ embeds, const float* __restrict__ centers,
        float* __restrict__ q, float* __restrict__ colsum_part, int nblocks)
{
    __shared__ float lds[4 * 128];
    const int tid  = threadIdx.x;
    const int wid  = tid >> 6;
    const int lane = tid & 63;
    const int m = lane & 15;   // A-row / B-col class
    const int g = lane >> 4;   // k-subgroup

    // ---- load centers fragments (held in registers for whole kernel) + cnorm
    bf16x8 bfrag[8][2];
    float cnorm[8];
    #pragma unroll
    for (int cb = 0; cb < 8; ++cb) {
        float cacc = 0.f;
        #pragma unroll
        for (int h = 0; h < 2; ++h) {
            const float* src = centers + (size_t)(cb * 16 + m) * DIMS + h * 32 + g * 8;
            f32x4 c0 = *(const f32x4*)src;
            f32x4 c1 = *(const f32x4*)(src + 4);
            bf16x8 b;
            #pragma unroll
            for (int j = 0; j < 4; ++j) {
                float f0 = c0[j], f1 = c1[j];
                cacc += f0 * f0 + f1 * f1;
                b[j]     = f2bf(f0);
                b[j + 4] = f2bf(f1);
            }
            bfrag[cb][h] = b;
        }
        cacc += __shfl_xor(cacc, 16);
        cacc += __shfl_xor(cacc, 32);
        cnorm[cb] = cacc;   // norm of center (cb*16 + m)
    }

    float csum[8];
    #pragma unroll
    for (int cb = 0; cb < 8; ++cb) csum[cb] = 0.f;

    const int gwid = blockIdx.x * 4 + wid;
    const int nw   = nblocks * 4;
    for (int t = gwid; t < NTILES; t += nw) {
        // ---- load A tile (16 rows), convert, e-norms
        bf16x8 afrag[2];
        float en = 0.f;
        #pragma unroll
        for (int h = 0; h < 2; ++h) {
            const float* src = embeds + (size_t)(t * 16 + m) * DIMS + h * 32 + g * 8;
            f32x4 c0 = *(const f32x4*)src;
            f32x4 c1 = *(const f32x4*)(src + 4);
            bf16x8 a;
            #pragma unroll
            for (int j = 0; j < 4; ++j) {
                float f0 = c0[j], f1 = c1[j];
                en += f0 * f0 + f1 * f1;
                a[j]     = f2bf(f0);
                a[j + 4] = f2bf(f1);
            }
            afrag[h] = a;
        }
        en += __shfl_xor(en, 16);
        en += __shfl_xor(en, 32);          // lane x now has norm of row (x&15)
        float er[4];
        #pragma unroll
        for (int r = 0; r < 4; ++r) er[r] = __shfl(en, g * 4 + r); // norm of row 4g+r

        // ---- MFMA: 8 col-blocks x 2 k-halves
        f32x4 acc[8];
        #pragma unroll
        for (int cb = 0; cb < 8; ++cb) {
            f32x4 a = {0.f, 0.f, 0.f, 0.f};
            a = __builtin_amdgcn_mfma_f32_16x16x32_bf16(afrag[0], bfrag[cb][0], a, 0, 0, 0);
            a = __builtin_amdgcn_mfma_f32_16x16x32_bf16(afrag[1], bfrag[cb][1], a, 0, 0, 0);
            acc[cb] = a;
        }

        // ---- student-t kernel + row sums
        float rs[4] = {0.f, 0.f, 0.f, 0.f};
        #pragma unroll
        for (int cb = 0; cb < 8; ++cb) {
            #pragma unroll
            for (int r = 0; r < 4; ++r) {
                float sq = er[r] + cnorm[cb] - 2.0f * acc[cb][r];
                sq = fmaxf(sq, 0.f);
                float dist = 1.0f / (1.0f + sq);
                acc[cb][r] = dist;
                rs[r] += dist;
            }
        }
        #pragma unroll
        for (int r = 0; r < 4; ++r) {
            rs[r] += __shfl_xor(rs[r], 1);
            rs[r] += __shfl_xor(rs[r], 2);
            rs[r] += __shfl_xor(rs[r], 4);
            rs[r] += __shfl_xor(rs[r], 8);  // sum over all 128 cols for row 4g+r
            rs[r] = 1.0f / rs[r];
        }

        // ---- q = dist/rowsum: store + column-sum accumulate
        #pragma unroll
        for (int cb = 0; cb < 8; ++cb) {
            #pragma unroll
            for (int r = 0; r < 4; ++r) {
                float qv = acc[cb][r] * rs[r];
                q[(size_t)(t * 16 + g * 4 + r) * KC + cb * 16 + m] = qv;
                csum[cb] += qv;
            }
        }
    }

    // ---- block-level column-sum partials (deterministic, no atomics)
    #pragma unroll
    for (int cb = 0; cb < 8; ++cb) {
        csum[cb] += __shfl_xor(csum[cb], 16);
        csum[cb] += __shfl_xor(csum[cb], 32);
    }
    if (lane < 16) {
        #pragma unroll
        for (int cb = 0; cb < 8; ++cb) lds[wid * 128 + cb * 16 + lane] = csum[cb];
    }
    __syncthreads();
    if (tid < 128) {
        float s = lds[tid] + lds[128 + tid] + lds[256 + tid] + lds[384 + tid];
        colsum_part[(size_t)blockIdx.x * 128 + tid] = s;
    }
}

// K1b: reduce per-block column partials -> S[k], logS[k]
__global__ __launch_bounds__(1024) void k1b_reduce(
        const float* __restrict__ part, float* __restrict__ S,
        float* __restrict__ logS, int nb)
{
    __shared__ float lds[8][128];
    const int tid = threadIdx.x;
    const int c = tid & 127, grp = tid >> 7;
    float s = 0.f;
    for (int b = grp; b < nb; b += 8) s += part[(size_t)b * 128 + c];
    lds[grp][c] = s;
    __syncthreads();
    if (tid < 128) {
        float tot = 0.f;
        #pragma unroll
        for (int g2 = 0; g2 < 8; ++g2) tot += lds[g2][tid];
        S[tid] = tot;
        logS[tid] = __logf(tot);
    }
}

// K2: wave-per-row; loss term = p*(log p - log q) = (w/W)*(log q - log S_k - log W)
__global__ __launch_bounds__(256) void k2_loss(
        const float* __restrict__ q, const float* __restrict__ S,
        const float* __restrict__ logS, float* __restrict__ losspart, int nblocks)
{
    __shared__ float lds[4];
    const int tid = threadIdx.x, wid = tid >> 6, lane = tid & 63;
    const float invS0 = 1.0f / S[lane];
    const float invS1 = 1.0f / S[lane + 64];
    const float lS0 = logS[lane];
    const float lS1 = logS[lane + 64];
    float acc = 0.f;
    const int gwid = blockIdx.x * 4 + wid;
    const int nw = nblocks * 4;
    for (int n = gwid; n < NROWS; n += nw) {
        float q0 = q[(size_t)n * KC + lane];
        float q1 = q[(size_t)n * KC + 64 + lane];
        float w0 = q0 * q0 * invS0;
        float w1 = q1 * q1 * invS1;
        float W = w0 + w1;
        W += __shfl_xor(W, 1);  W += __shfl_xor(W, 2);  W += __shfl_xor(W, 4);
        W += __shfl_xor(W, 8);  W += __shfl_xor(W, 16); W += __shfl_xor(W, 32);
        float invW = 1.0f / W;
        float logW = __logf(W);
        acc += w0 * invW * (__logf(q0) - lS0 - logW)
             + w1 * invW * (__logf(q1) - lS1 - logW);
    }
    acc += __shfl_xor(acc, 1);  acc += __shfl_xor(acc, 2);  acc += __shfl_xor(acc, 4);
    acc += __shfl_xor(acc, 8);  acc += __shfl_xor(acc, 16); acc += __shfl_xor(acc, 32);
    if (lane == 0) lds[wid] = acc;
    __syncthreads();
    if (tid == 0) losspart[blockIdx.x] = lds[0] + lds[1] + lds[2] + lds[3];
}

// K2b: final loss reduce
__global__ __launch_bounds__(1024) void k2b_final(
        const float* __restrict__ losspart, int nb, float* __restrict__ out)
{
    __shared__ float lds[16];
    const int tid = threadIdx.x;
    float s = 0.f;
    for (int b = tid; b < nb; b += 1024) s += losspart[b];
    s += __shfl_xor(s, 1);  s += __shfl_xor(s, 2);  s += __shfl_xor(s, 4);
    s += __shfl_xor(s, 8);  s += __shfl_xor(s, 16); s += __shfl_xor(s, 32);
    if ((tid & 63) == 0) lds[tid >> 6] = s;
    __syncthreads();
    if (tid == 0) {
        float tot = 0.f;
        #pragma unroll
        for (int i = 0; i < 16; ++i) tot += lds[i];
        out[0] = (float)((double)tot / (double)((size_t)NROWS * KC));
    }
}

extern "C" void kernel_launch(void* const* d_in, const int* in_sizes, int n_in,
                              void* d_out, int out_size, void* d_ws, size_t ws_size,
                              hipStream_t stream)
{
    const float* embeds  = (const float*)d_in[0];
    const float* centers = (const float*)d_in[1];
    float* out  = (float*)d_out;
    float* qbuf = out + 1;              // q starts after the scalar loss
    float* ws   = (float*)d_ws;

    int GB1 = 768, GB2 = 1024;
    size_t need = ((size_t)GB1 * 128 + 256 + (size_t)GB2) * sizeof(float);
    if (need > ws_size) { GB1 = 128; GB2 = 256; }   // conservative fallback

    float* colsum_part = ws;
    float* S     = ws + (size_t)GB1 * 128;
    float* logS  = S + 128;
    float* lpart = logS + 128;

    hipLaunchKernelGGL(k1_qcolsum, dim3(GB1), dim3(256), 0, stream,
                       embeds, centers, qbuf, colsum_part, GB1);
    hipLaunchKernelGGL(k1b_reduce, dim3(1), dim3(1024), 0, stream,
                       colsum_part, S, logS, GB1);
    hipLaunchKernelGGL(k2_loss, dim3(GB2), dim3(256), 0, stream,
                       qbuf, S, logS, lpart, GB2);
    hipLaunchKernelGGL(k2b_final, dim3(1), dim3(1024), 0, stream,
                       lpart, GB2, out);
}

// Round 2
// 123.301 us; speedup vs baseline: 1.4292x; 1.4292x over previous
//
#include <hip/hip_runtime.h>
#include <stdint.h>
#include <stddef.h>

typedef __attribute__((ext_vector_type(8))) short bf16x8;
typedef __attribute__((ext_vector_type(4))) float f32x4;

#define NROWS 400000
#define KC 128
#define DIMS 64
#define NTILES (NROWS / 16)

__device__ __forceinline__ short f2bf(float f) {
    union { float f; uint32_t u; } v; v.f = f;
    uint32_t u = v.u;
    uint32_t r = (u + 0x7FFFu + ((u >> 16) & 1u)) >> 16;  // RNE, finite inputs
    return (short)r;
}

__device__ __forceinline__ float frcp(float x) { return __builtin_amdgcn_rcpf(x); }

// Shared helper: stage center bf16 fragments into LDS (wave 0), return cnorm in regs.
// B-fragment layout for mfma_16x16x32_bf16: lane (m,g) holds B[8g+i][m], i=0..7, per k-half.
__device__ __forceinline__ void stage_centers(
        const float* __restrict__ centers, bf16x8 (*blds)[2][64],
        float* cnorm, int wid, int lane, int m, int g)
{
    #pragma unroll
    for (int cb = 0; cb < 8; ++cb) {
        float cacc = 0.f;
        bf16x8 bfr[2];
        #pragma unroll
        for (int h = 0; h < 2; ++h) {
            const float* src = centers + (size_t)(cb * 16 + m) * DIMS + h * 32 + g * 8;
            f32x4 c0 = *(const f32x4*)src;
            f32x4 c1 = *(const f32x4*)(src + 4);
            bf16x8 b;
            #pragma unroll
            for (int j = 0; j < 4; ++j) {
                float f0 = c0[j], f1 = c1[j];
                cacc += f0 * f0 + f1 * f1;
                b[j]     = f2bf(f0);
                b[j + 4] = f2bf(f1);
            }
            bfr[h] = b;
        }
        cacc += __shfl_xor(cacc, 16);
        cacc += __shfl_xor(cacc, 32);
        cnorm[cb] = cacc;
        if (wid == 0) { blds[cb][0][lane] = bfr[0]; blds[cb][1][lane] = bfr[1]; }
    }
    __syncthreads();
}

// K1: column sums of q. Reads embeds only; writes per-block colsum partials.
__global__ __launch_bounds__(256) void k1_colsum(
        const float* __restrict__ embeds, const float* __restrict__ centers,
        float* __restrict__ colsum_part, int nblocks)
{
    __shared__ bf16x8 blds[8][2][64];
    __shared__ float cl[4 * 128];
    const int tid = threadIdx.x, wid = tid >> 6, lane = tid & 63;
    const int m = lane & 15, g = lane >> 4;

    float cnorm[8];
    stage_centers(centers, blds, cnorm, wid, lane, m, g);

    float csum[8];
    #pragma unroll
    for (int cb = 0; cb < 8; ++cb) csum[cb] = 0.f;

    const int gwid = blockIdx.x * 4 + wid;
    const int nw = nblocks * 4;

    int t = gwid;
    f32x4 n0, n1, n2, n3;
    {
        const float* src = embeds + (size_t)(t * 16 + m) * DIMS + g * 8;
        n0 = *(const f32x4*)src;       n1 = *(const f32x4*)(src + 4);
        n2 = *(const f32x4*)(src + 32); n3 = *(const f32x4*)(src + 36);
    }
    for (; t < NTILES; t += nw) {
        f32x4 c0 = n0, c1 = n1, c2 = n2, c3 = n3;
        int tn = t + nw;
        if (tn < NTILES) {
            const float* src = embeds + (size_t)(tn * 16 + m) * DIMS + g * 8;
            n0 = *(const f32x4*)src;       n1 = *(const f32x4*)(src + 4);
            n2 = *(const f32x4*)(src + 32); n3 = *(const f32x4*)(src + 36);
        }
        // convert + embed norms
        bf16x8 a0, a1;
        float en = 0.f;
        #pragma unroll
        for (int j = 0; j < 4; ++j) {
            float f0 = c0[j], f1 = c1[j], f2 = c2[j], f3 = c3[j];
            en += f0 * f0 + f1 * f1 + f2 * f2 + f3 * f3;
            a0[j] = f2bf(f0); a0[j + 4] = f2bf(f1);
            a1[j] = f2bf(f2); a1[j + 4] = f2bf(f3);
        }
        en += __shfl_xor(en, 16);
        en += __shfl_xor(en, 32);
        float er[4];
        #pragma unroll
        for (int r = 0; r < 4; ++r) er[r] = __shfl(en, g * 4 + r);

        f32x4 acc[8];
        #pragma unroll
        for (int cb = 0; cb < 8; ++cb) {
            bf16x8 b0 = blds[cb][0][lane];
            bf16x8 b1 = blds[cb][1][lane];
            f32x4 a = {0.f, 0.f, 0.f, 0.f};
            a = __builtin_amdgcn_mfma_f32_16x16x32_bf16(a0, b0, a, 0, 0, 0);
            a = __builtin_amdgcn_mfma_f32_16x16x32_bf16(a1, b1, a, 0, 0, 0);
            acc[cb] = a;
        }

        float rs[4] = {0.f, 0.f, 0.f, 0.f};
        #pragma unroll
        for (int cb = 0; cb < 8; ++cb) {
            #pragma unroll
            for (int r = 0; r < 4; ++r) {
                float sq = fmaxf(er[r] + cnorm[cb] - 2.0f * acc[cb][r], 0.f);
                float dist = frcp(1.0f + sq);
                acc[cb][r] = dist;
                rs[r] += dist;
            }
        }
        #pragma unroll
        for (int r = 0; r < 4; ++r) {
            rs[r] += __shfl_xor(rs[r], 1);
            rs[r] += __shfl_xor(rs[r], 2);
            rs[r] += __shfl_xor(rs[r], 4);
            rs[r] += __shfl_xor(rs[r], 8);
            rs[r] = frcp(rs[r]);
        }
        #pragma unroll
        for (int cb = 0; cb < 8; ++cb) {
            #pragma unroll
            for (int r = 0; r < 4; ++r) csum[cb] += acc[cb][r] * rs[r];
        }
    }

    #pragma unroll
    for (int cb = 0; cb < 8; ++cb) {
        csum[cb] += __shfl_xor(csum[cb], 16);
        csum[cb] += __shfl_xor(csum[cb], 32);
    }
    if (lane < 16) {
        #pragma unroll
        for (int cb = 0; cb < 8; ++cb) cl[wid * 128 + cb * 16 + lane] = csum[cb];
    }
    __syncthreads();
    if (tid < 128) {
        float s = cl[tid] + cl[128 + tid] + cl[256 + tid] + cl[384 + tid];
        colsum_part[(size_t)blockIdx.x * 128 + tid] = s;
    }
}

// K1b: reduce partials -> invS, logS
__global__ __launch_bounds__(1024) void k1b_reduce(
        const float* __restrict__ part, float* __restrict__ invS,
        float* __restrict__ lS, int nb)
{
    __shared__ float lds[8][128];
    const int tid = threadIdx.x;
    const int c = tid & 127, grp = tid >> 7;
    float s = 0.f;
    for (int b = grp; b < nb; b += 8) s += part[(size_t)b * 128 + c];
    lds[grp][c] = s;
    __syncthreads();
    if (tid < 128) {
        float tot = 0.f;
        #pragma unroll
        for (int g2 = 0; g2 < 8; ++g2) tot += lds[g2][tid];
        invS[tid] = 1.0f / tot;
        lS[tid] = __logf(tot);
    }
}

// K2: recompute dist (same deterministic path), write q, fused loss.
__global__ __launch_bounds__(256) void k2_q_loss(
        const float* __restrict__ embeds, const float* __restrict__ centers,
        const float* __restrict__ invS, const float* __restrict__ lS,
        float* __restrict__ q, float* __restrict__ losspart, int nblocks)
{
    __shared__ bf16x8 blds[8][2][64];
    __shared__ float lds4[4];
    const int tid = threadIdx.x, wid = tid >> 6, lane = tid & 63;
    const int m = lane & 15, g = lane >> 4;

    float cnorm[8];
    stage_centers(centers, blds, cnorm, wid, lane, m, g);

    float invSr[8], lSr[8];
    #pragma unroll
    for (int cb = 0; cb < 8; ++cb) {
        invSr[cb] = invS[cb * 16 + m];
        lSr[cb]   = lS[cb * 16 + m];
    }

    float loss = 0.f;
    const int gwid = blockIdx.x * 4 + wid;
    const int nw = nblocks * 4;

    int t = gwid;
    f32x4 n0, n1, n2, n3;
    {
        const float* src = embeds + (size_t)(t * 16 + m) * DIMS + g * 8;
        n0 = *(const f32x4*)src;       n1 = *(const f32x4*)(src + 4);
        n2 = *(const f32x4*)(src + 32); n3 = *(const f32x4*)(src + 36);
    }
    for (; t < NTILES; t += nw) {
        f32x4 c0 = n0, c1 = n1, c2 = n2, c3 = n3;
        int tn = t + nw;
        if (tn < NTILES) {
            const float* src = embeds + (size_t)(tn * 16 + m) * DIMS + g * 8;
            n0 = *(const f32x4*)src;       n1 = *(const f32x4*)(src + 4);
            n2 = *(const f32x4*)(src + 32); n3 = *(const f32x4*)(src + 36);
        }
        bf16x8 a0, a1;
        float en = 0.f;
        #pragma unroll
        for (int j = 0; j < 4; ++j) {
            float f0 = c0[j], f1 = c1[j], f2 = c2[j], f3 = c3[j];
            en += f0 * f0 + f1 * f1 + f2 * f2 + f3 * f3;
            a0[j] = f2bf(f0); a0[j + 4] = f2bf(f1);
            a1[j] = f2bf(f2); a1[j + 4] = f2bf(f3);
        }
        en += __shfl_xor(en, 16);
        en += __shfl_xor(en, 32);
        float er[4];
        #pragma unroll
        for (int r = 0; r < 4; ++r) er[r] = __shfl(en, g * 4 + r);

        f32x4 acc[8];
        #pragma unroll
        for (int cb = 0; cb < 8; ++cb) {
            bf16x8 b0 = blds[cb][0][lane];
            bf16x8 b1 = blds[cb][1][lane];
            f32x4 a = {0.f, 0.f, 0.f, 0.f};
            a = __builtin_amdgcn_mfma_f32_16x16x32_bf16(a0, b0, a, 0, 0, 0);
            a = __builtin_amdgcn_mfma_f32_16x16x32_bf16(a1, b1, a, 0, 0, 0);
            acc[cb] = a;
        }

        // dist + identical row-sum recompute
        float rs[4] = {0.f, 0.f, 0.f, 0.f};
        #pragma unroll
        for (int cb = 0; cb < 8; ++cb) {
            #pragma unroll
            for (int r = 0; r < 4; ++r) {
                float sq = fmaxf(er[r] + cnorm[cb] - 2.0f * acc[cb][r], 0.f);
                float dist = frcp(1.0f + sq);
                acc[cb][r] = dist;
                rs[r] += dist;
            }
        }
        #pragma unroll
        for (int r = 0; r < 4; ++r) {
            rs[r] += __shfl_xor(rs[r], 1);
            rs[r] += __shfl_xor(rs[r], 2);
            rs[r] += __shfl_xor(rs[r], 4);
            rs[r] += __shfl_xor(rs[r], 8);
            rs[r] = frcp(rs[r]);
        }

        // q = dist * invR: store + w accumulation
        float W[4] = {0.f, 0.f, 0.f, 0.f};
        #pragma unroll
        for (int cb = 0; cb < 8; ++cb) {
            #pragma unroll
            for (int r = 0; r < 4; ++r) {
                float qv = acc[cb][r] * rs[r];
                acc[cb][r] = qv;
                q[(size_t)(t * 16 + g * 4 + r) * KC + cb * 16 + m] = qv;
                W[r] += qv * qv * invSr[cb];
            }
        }
        float iw[4], lw[4];
        #pragma unroll
        for (int r = 0; r < 4; ++r) {
            W[r] += __shfl_xor(W[r], 1);
            W[r] += __shfl_xor(W[r], 2);
            W[r] += __shfl_xor(W[r], 4);
            W[r] += __shfl_xor(W[r], 8);
            iw[r] = frcp(W[r]);
            lw[r] = __logf(W[r]);
        }
        #pragma unroll
        for (int cb = 0; cb < 8; ++cb) {
            #pragma unroll
            for (int r = 0; r < 4; ++r) {
                float qv = acc[cb][r];
                float w = qv * qv * invSr[cb];
                loss += w * iw[r] * (__logf(qv) - lSr[cb] - lw[r]);
            }
        }
    }

    loss += __shfl_xor(loss, 1);  loss += __shfl_xor(loss, 2);
    loss += __shfl_xor(loss, 4);  loss += __shfl_xor(loss, 8);
    loss += __shfl_xor(loss, 16); loss += __shfl_xor(loss, 32);
    if (lane == 0) lds4[wid] = loss;
    __syncthreads();
    if (tid == 0) losspart[blockIdx.x] = lds4[0] + lds4[1] + lds4[2] + lds4[3];
}

// K2b: final loss reduce
__global__ __launch_bounds__(1024) void k2b_final(
        const float* __restrict__ losspart, int nb, float* __restrict__ out)
{
    __shared__ float lds[16];
    const int tid = threadIdx.x;
    float s = 0.f;
    for (int b = tid; b < nb; b += 1024) s += losspart[b];
    s += __shfl_xor(s, 1);  s += __shfl_xor(s, 2);  s += __shfl_xor(s, 4);
    s += __shfl_xor(s, 8);  s += __shfl_xor(s, 16); s += __shfl_xor(s, 32);
    if ((tid & 63) == 0) lds[tid >> 6] = s;
    __syncthreads();
    if (tid == 0) {
        float tot = 0.f;
        #pragma unroll
        for (int i = 0; i < 16; ++i) tot += lds[i];
        out[0] = (float)((double)tot / (double)((size_t)NROWS * KC));
    }
}

extern "C" void kernel_launch(void* const* d_in, const int* in_sizes, int n_in,
                              void* d_out, int out_size, void* d_ws, size_t ws_size,
                              hipStream_t stream)
{
    const float* embeds  = (const float*)d_in[0];
    const float* centers = (const float*)d_in[1];
    float* out  = (float*)d_out;
    float* qbuf = out + 1;
    float* ws   = (float*)d_ws;

    const int GB1 = 512, GB2 = 512;
    float* colsum_part = ws;                          // GB1*128
    float* invS  = ws + (size_t)GB1 * 128;            // 128
    float* lS    = invS + 128;                        // 128
    float* lpart = lS + 128;                          // GB2

    hipLaunchKernelGGL(k1_colsum, dim3(GB1), dim3(256), 0, stream,
                       embeds, centers, colsum_part, GB1);
    hipLaunchKernelGGL(k1b_reduce, dim3(1), dim3(1024), 0, stream,
                       colsum_part, invS, lS, GB1);
    hipLaunchKernelGGL(k2_q_loss, dim3(GB2), dim3(256), 0, stream,
                       embeds, centers, invS, lS, qbuf, lpart, GB2);
    hipLaunchKernelGGL(k2b_final, dim3(1), dim3(1024), 0, stream,
                       lpart, GB2, out);
}